// Round 7
// baseline (165.526 us; speedup 1.0000x reference)
//
#include <hip/hip_runtime.h>
#include <cmath>

// Problem constants: B=32768, N=17, D=2, K=3, H=64
#define NBATCH 32768
#define NJOINT 17
#define OUT0_ELEMS (NBATCH * NJOINT * 15)          // out[B,N,3,5]
#define KJS_OFF    OUT0_ELEMS                      // k_js[B,N]
#define MASK_OFF   (KJS_OFF + NBATCH * NJOINT)     // mask[B,N,3]

// fp64 weight workspace (escape path only), per joint n stride 774 doubles:
//  [0,64) W1a | [64,128) W1b | [128,192) b1 | [192,384) W2[h][3] | [384,387) b2
//  +387 same for w-MLP
#define WN_STRIDE 774
#define WS_DOUBLES (NJOINT * WN_STRIDE)

// bMLP LDS blob: h-groups of 16 floats {W1a[h], W1b[h], b1[h], pad, W2[h][0..11]},
// h=0..127, then [2048,2060) = bb2[0..11]. All groups 16B-aligned -> float4 reads.
#define BW_FLT 2064

__device__ __forceinline__ float sel3f(int i, float a, float b, float c) {
    return (i == 0) ? a : ((i == 1) ? b : c);
}

// --------------------------------------------------------------------------
// Prelude: fp64 copies of k/w weights (used only by the rare escape path).
// --------------------------------------------------------------------------
__global__ void cvt_weights_f64(
    const float* __restrict__ kW1, const float* __restrict__ kb1,
    const float* __restrict__ kW2, const float* __restrict__ kb2,
    const float* __restrict__ wW1, const float* __restrict__ wb1,
    const float* __restrict__ wW2, const float* __restrict__ wb2,
    double* __restrict__ dws)
{
    const int n = blockIdx.x;
    double* o = dws + (size_t)n * WN_STRIDE;
    for (int i = threadIdx.x; i < WN_STRIDE; i += blockDim.x) {
        int j = i;
        const float* W1 = kW1; const float* b1 = kb1;
        const float* W2 = kW2; const float* b2 = kb2;
        if (j >= 387) { j -= 387; W1 = wW1; b1 = wb1; W2 = wW2; b2 = wb2; }
        float v;
        if (j < 128)      v = W1[n * 128 + j];
        else if (j < 192) v = b1[n * 64 + (j - 128)];
        else if (j < 384) v = W2[n * 192 + (j - 192)];
        else              v = b2[n * 3 + (j - 384)];
        o[i] = (double)v;
    }
}

// --------------------------------------------------------------------------
// fp32 MLP (2 -> 64 -> 3) for TWO points, one s_load weight stream.
// --------------------------------------------------------------------------
__device__ __forceinline__ void mlp32_2(
    const float* __restrict__ W1, const float* __restrict__ b1f,
    const float* __restrict__ W2f, const float* __restrict__ b2f, int n,
    float xA0, float xA1, float xB0, float xB1,
    float& lA0, float& lA1, float& lA2,
    float& lB0, float& lB1, float& lB2)
{
    const float* W1a = W1 + n * 128;
    const float* W1b = W1a + 64;
    const float* b1  = b1f + n * 64;
    const float* W2  = W2f + n * 192;
    lA0 = b2f[n * 3 + 0]; lB0 = lA0;
    lA1 = b2f[n * 3 + 1]; lB1 = lA1;
    lA2 = b2f[n * 3 + 2]; lB2 = lA2;
    #pragma unroll 4
    for (int h = 0; h < 64; ++h) {
        const float wa = W1a[h], wb = W1b[h], bb = b1[h];
        const float w0 = W2[h * 3 + 0], w1 = W2[h * 3 + 1], w2 = W2[h * 3 + 2];
        float hvA = fmaxf(fmaf(xA1, wb, fmaf(xA0, wa, bb)), 0.0f);
        float hvB = fmaxf(fmaf(xB1, wb, fmaf(xB0, wa, bb)), 0.0f);
        lA0 = fmaf(hvA, w0, lA0); lB0 = fmaf(hvB, w0, lB0);
        lA1 = fmaf(hvA, w1, lA1); lB1 = fmaf(hvB, w1, lB1);
        lA2 = fmaf(hvA, w2, lA2); lB2 = fmaf(hvB, w2, lB2);
    }
}

// --------------------------------------------------------------------------
// fp64 escape: EXACT sequence of the proven passing kernels (ws layout).
// --------------------------------------------------------------------------
__device__ __forceinline__ void mlp64_ws_1(
    const double* __restrict__ gws, double x0, double x1,
    double& l0, double& l1, double& l2)
{
    const double* W1a = gws;
    const double* W1b = gws + 64;
    const double* b1  = gws + 128;
    const double* W2  = gws + 192;
    l0 = gws[384]; l1 = gws[385]; l2 = gws[386];
    #pragma unroll 4
    for (int h = 0; h < 64; ++h) {
        double hv = fmax(fma(x1, W1b[h], fma(x0, W1a[h], b1[h])), 0.0);
        l0 = fma(hv, W2[h * 3 + 0], l0);
        l1 = fma(hv, W2[h * 3 + 1], l1);
        l2 = fma(hv, W2[h * 3 + 2], l2);
    }
}

// fp64 escape without ws: cvt-in-loop, identical to original fallback sequence
__device__ __forceinline__ void mlp64_cvt_1(
    const float* __restrict__ W1, const float* __restrict__ b1f,
    const float* __restrict__ W2f, const float* __restrict__ b2f, int n,
    double x0, double x1, double& l0, double& l1, double& l2)
{
    const float* W1a = W1 + n * 128;
    const float* W1b = W1a + 64;
    const float* b1  = b1f + n * 64;
    const float* W2  = W2f + n * 192;
    l0 = (double)b2f[n * 3 + 0];
    l1 = (double)b2f[n * 3 + 1];
    l2 = (double)b2f[n * 3 + 2];
    #pragma unroll 4
    for (int h = 0; h < 64; ++h) {
        double hv = fma(x1, (double)W1b[h], fma(x0, (double)W1a[h], (double)b1[h]));
        hv = fmax(hv, 0.0);
        l0 = fma(hv, (double)W2[h * 3 + 0], l0);
        l1 = fma(hv, (double)W2[h * 3 + 1], l1);
        l2 = fma(hv, (double)W2[h * 3 + 2], l2);
    }
}

// margin check: true if any pair of logits is too close to trust fp32 ordering.
// tau >= 3x worst-case fp32 64-term fma-chain error (~1.5e-4 at |l|~O(1)),
// magnitude-scaled.
__device__ __forceinline__ bool tight3(float a, float b, float c) {
    const float m01 = fabsf(a - b), m02 = fabsf(a - c), m12 = fabsf(b - c);
    const float mn = fminf(m01, fminf(m02, m12));
    const float tau = 1e-3f * (1.0f + 0.02f * (fabsf(a) + fabsf(b) + fabsf(c)));
    return mn < tau;
}

// decisions + softmax from (double) logits — identical to passing kernels.
__device__ __forceinline__ void decide(
    double kl0, double kl1, double kl2,
    double wl0, double wl1, double wl2,
    int& kj, int& i0, int& i1, int& i2,
    float& p0, float& p1, float& p2)
{
    kj = 0;
    {
        double m = kl0;
        if (kl1 > m) { m = kl1; kj = 1; }
        if (kl2 > m) { kj = 2; }
    }
    i0 = 0;
    {
        double m = wl0;
        if (wl1 > m) { m = wl1; i0 = 1; }
        if (wl2 > m) { i0 = 2; }
    }
    const int ia = (i0 == 0) ? 1 : 0;
    const int ib = (i0 == 2) ? 1 : 2;
    const double wa = ia ? wl1 : wl0;
    const double wb = (ib == 1) ? wl1 : wl2;
    i1 = (wb > wa) ? ib : ia;
    i2 = (wb > wa) ? ia : ib;

    const double mw = fmax(fmax(wl0, wl1), wl2);
    const float e0 = __expf((float)(wl0 - mw));
    const float e1 = __expf((float)(wl1 - mw));
    const float e2 = __expf((float)(wl2 - mw));
    const float inv = 1.0f / (e0 + e1 + e2);
    p0 = e0 * inv; p1 = e1 * inv; p2 = e2 * inv;
}

__device__ __forceinline__ void epilogue(
    const float acc[12], int i0, int i1, int i2,
    float p0, float p1, float p2, float r[15])
{
    r[0]  = p0; r[5] = p1; r[10] = p2;
    r[1]  = sel3f(i0, acc[0], acc[4], acc[8]);
    r[2]  = sel3f(i0, acc[1], acc[5], acc[9]);
    r[3]  = __expf(sel3f(i0, acc[2], acc[6], acc[10]));
    r[4]  = __expf(sel3f(i0, acc[3], acc[7], acc[11]));
    r[6]  = sel3f(i1, acc[0], acc[4], acc[8]);
    r[7]  = sel3f(i1, acc[1], acc[5], acc[9]);
    r[8]  = __expf(sel3f(i1, acc[2], acc[6], acc[10]));
    r[9]  = __expf(sel3f(i1, acc[3], acc[7], acc[11]));
    r[11] = sel3f(i2, acc[0], acc[4], acc[8]);
    r[12] = sel3f(i2, acc[1], acc[5], acc[9]);
    r[13] = __expf(sel3f(i2, acc[2], acc[6], acc[10]));
    r[14] = __expf(sel3f(i2, acc[3], acc[7], acc[11]));
}

__device__ __forceinline__ void store_point(
    float* __restrict__ out, int p, const float r[15], int kj)
{
    float* o = out + (size_t)p * 15;
    #pragma unroll
    for (int i = 0; i < 15; ++i) o[i] = r[i];
    out[KJS_OFF + p] = (float)(kj + 1);
    float* mk = out + MASK_OFF + (size_t)p * 3;
    mk[0] = 1.0f;
    mk[1] = (kj >= 1) ? 1.0f : 0.0f;
    mk[2] = (kj >= 2) ? 1.0f : 0.0f;
}

// --------------------------------------------------------------------------
// Block = 256 threads, ONE joint n per block (n = bid>>6, n-major dispatch:
// 64 consecutive blocks share n -> per-CU scalar working set = k/w fp32 only
// (~3KB x few n) -> K$-resident). bMLP weights staged once in LDS (float4
// uniform broadcasts). 2 points per lane. fp32 k/w with fp64 margin-escape;
// bMLP bit-identical fp32; decisions guarded-identical to passing kernels.
// No early returns; single barrier.
// --------------------------------------------------------------------------
template<bool USE_WS>
__global__ __launch_bounds__(256, 4) void mdn_fused(
    const float* __restrict__ pred_pts,
    const float* __restrict__ kW1, const float* __restrict__ kb1,
    const float* __restrict__ kW2, const float* __restrict__ kb2,
    const float* __restrict__ wW1, const float* __restrict__ wb1,
    const float* __restrict__ wW2, const float* __restrict__ wb2,
    const float* __restrict__ bW1, const float* __restrict__ bb1,
    const float* __restrict__ bW2, const float* __restrict__ bb2,
    float* __restrict__ out,
    const double* __restrict__ dws)
{
    const int tid = threadIdx.x;
    const int bid = blockIdx.x;        // 0..1087
    const int n   = bid >> 6;          // 0..16 (uniform per block)
    const int bxx = bid & 63;

    // ---- stage bMLP weights for this n into LDS (gather proven in r3) ----
    __shared__ __align__(16) float bw[BW_FLT];
    for (int j = tid; j < BW_FLT; j += 256) {
        const int g = j >> 4, s = j & 15;
        float f;
        if (g < 128) {
            f = (s == 0) ? bW1[n * 256 + g]
              : (s == 1) ? bW1[n * 256 + 128 + g]
              : (s == 2) ? bb1[n * 128 + g]
              : (s == 3) ? 0.0f
              :            bW2[n * 1536 + g * 12 + (s - 4)];
        } else {
            f = (s < 12) ? bb2[n * 12 + s] : 0.0f;
        }
        bw[j] = f;
    }

    const int bA = bxx * 512 + tid;
    const int bB = bA + 256;
    const int pA = bA * NJOINT + n;
    const int pB = bB * NJOINT + n;
    const float2 xA = *reinterpret_cast<const float2*>(pred_pts + 2 * pA);
    const float2 xB = *reinterpret_cast<const float2*>(pred_pts + 2 * pB);

    __syncthreads();

    // ---- k & w MLPs in fp32 (shared s_load stream, 2 pts) ----
    float kA0, kA1, kA2, kB0, kB1, kB2;
    float wA0, wA1, wA2, wB0, wB1, wB2;
    mlp32_2(kW1, kb1, kW2, kb2, n, xA.x, xA.y, xB.x, xB.y,
            kA0, kA1, kA2, kB0, kB1, kB2);
    mlp32_2(wW1, wb1, wW2, wb2, n, xA.x, xA.y, xB.x, xB.y,
            wA0, wA1, wA2, wB0, wB1, wB2);

    const bool fA = tight3(kA0, kA1, kA2) || tight3(wA0, wA1, wA2);
    const bool fB = tight3(kB0, kB1, kB2) || tight3(wB0, wB1, wB2);

    double klA0 = kA0, klA1 = kA1, klA2 = kA2;
    double klB0 = kB0, klB1 = kB1, klB2 = kB2;
    double wlA0 = wA0, wlA1 = wA1, wlA2 = wA2;
    double wlB0 = wB0, wlB1 = wB1, wlB2 = wB2;

    if (__any(fA || fB)) {             // rare (~15% of waves): exact fp64 redo
        if constexpr (USE_WS) {
            const double* Wn = dws + (size_t)n * WN_STRIDE;
            if (fA) {
                mlp64_ws_1(Wn,       (double)xA.x, (double)xA.y, klA0, klA1, klA2);
                mlp64_ws_1(Wn + 387, (double)xA.x, (double)xA.y, wlA0, wlA1, wlA2);
            }
            if (fB) {
                mlp64_ws_1(Wn,       (double)xB.x, (double)xB.y, klB0, klB1, klB2);
                mlp64_ws_1(Wn + 387, (double)xB.x, (double)xB.y, wlB0, wlB1, wlB2);
            }
        } else {
            if (fA) {
                mlp64_cvt_1(kW1, kb1, kW2, kb2, n, (double)xA.x, (double)xA.y, klA0, klA1, klA2);
                mlp64_cvt_1(wW1, wb1, wW2, wb2, n, (double)xA.x, (double)xA.y, wlA0, wlA1, wlA2);
            }
            if (fB) {
                mlp64_cvt_1(kW1, kb1, kW2, kb2, n, (double)xB.x, (double)xB.y, klB0, klB1, klB2);
                mlp64_cvt_1(wW1, wb1, wW2, wb2, n, (double)xB.x, (double)xB.y, wlB0, wlB1, wlB2);
            }
        }
    }

    int kjA, i0A, i1A, i2A, kjB, i0B, i1B, i2B;
    float p0A, p1A, p2A, p0B, p1B, p2B;
    decide(klA0, klA1, klA2, wlA0, wlA1, wlA2, kjA, i0A, i1A, i2A, p0A, p1A, p2A);
    decide(klB0, klB1, klB2, wlB0, wlB1, wlB2, kjB, i0B, i1B, i2B, p0B, p1B, p2B);

    // ---- bMLP (fp32, bit-identical order) from LDS float4 broadcasts ----
    float accA[12], accB[12];
    #pragma unroll
    for (int j = 0; j < 12; ++j) { const float t = bw[2048 + j]; accA[j] = t; accB[j] = t; }
    #pragma unroll 4
    for (int h = 0; h < 128; ++h) {
        const float4* g4 = reinterpret_cast<const float4*>(bw + (h << 4));
        const float4 q0 = g4[0], q1 = g4[1], q2 = g4[2], q3 = g4[3];
        const float hvA = fmaxf(fmaf(xA.y, q0.y, fmaf(xA.x, q0.x, q0.z)), 0.0f);
        const float hvB = fmaxf(fmaf(xB.y, q0.y, fmaf(xB.x, q0.x, q0.z)), 0.0f);
        accA[0]  = fmaf(hvA, q1.x, accA[0]);  accB[0]  = fmaf(hvB, q1.x, accB[0]);
        accA[1]  = fmaf(hvA, q1.y, accA[1]);  accB[1]  = fmaf(hvB, q1.y, accB[1]);
        accA[2]  = fmaf(hvA, q1.z, accA[2]);  accB[2]  = fmaf(hvB, q1.z, accB[2]);
        accA[3]  = fmaf(hvA, q1.w, accA[3]);  accB[3]  = fmaf(hvB, q1.w, accB[3]);
        accA[4]  = fmaf(hvA, q2.x, accA[4]);  accB[4]  = fmaf(hvB, q2.x, accB[4]);
        accA[5]  = fmaf(hvA, q2.y, accA[5]);  accB[5]  = fmaf(hvB, q2.y, accB[5]);
        accA[6]  = fmaf(hvA, q2.z, accA[6]);  accB[6]  = fmaf(hvB, q2.z, accB[6]);
        accA[7]  = fmaf(hvA, q2.w, accA[7]);  accB[7]  = fmaf(hvB, q2.w, accB[7]);
        accA[8]  = fmaf(hvA, q3.x, accA[8]);  accB[8]  = fmaf(hvB, q3.x, accB[8]);
        accA[9]  = fmaf(hvA, q3.y, accA[9]);  accB[9]  = fmaf(hvB, q3.y, accB[9]);
        accA[10] = fmaf(hvA, q3.z, accA[10]); accB[10] = fmaf(hvB, q3.z, accB[10]);
        accA[11] = fmaf(hvA, q3.w, accA[11]); accB[11] = fmaf(hvB, q3.w, accB[11]);
    }

    float rA[15], rB[15];
    epilogue(accA, i0A, i1A, i2A, p0A, p1A, p2A, rA);
    epilogue(accB, i0B, i1B, i2B, p0B, p1B, p2B, rB);

    store_point(out, pA, rA, kjA);
    store_point(out, pB, rB, kjB);
}

extern "C" void kernel_launch(void* const* d_in, const int* in_sizes, int n_in,
                              void* d_out, int out_size, void* d_ws, size_t ws_size,
                              hipStream_t stream) {
    (void)in_sizes; (void)n_in; (void)out_size;
    const bool use_ws = (d_ws != nullptr) && (ws_size >= (size_t)WS_DOUBLES * sizeof(double));
    dim3 grid(NJOINT * 64);            // 1088 blocks, n-major (n = bid>>6)
    if (use_ws) {
        cvt_weights_f64<<<NJOINT, 256, 0, stream>>>(
            (const float*)d_in[1], (const float*)d_in[2],
            (const float*)d_in[3], (const float*)d_in[4],
            (const float*)d_in[5], (const float*)d_in[6],
            (const float*)d_in[7], (const float*)d_in[8],
            (double*)d_ws);
        mdn_fused<true><<<grid, 256, 0, stream>>>(
            (const float*)d_in[0],
            (const float*)d_in[1], (const float*)d_in[2],
            (const float*)d_in[3], (const float*)d_in[4],
            (const float*)d_in[5], (const float*)d_in[6],
            (const float*)d_in[7], (const float*)d_in[8],
            (const float*)d_in[9], (const float*)d_in[10],
            (const float*)d_in[11], (const float*)d_in[12],
            (float*)d_out, (const double*)d_ws);
    } else {
        mdn_fused<false><<<grid, 256, 0, stream>>>(
            (const float*)d_in[0],
            (const float*)d_in[1], (const float*)d_in[2],
            (const float*)d_in[3], (const float*)d_in[4],
            (const float*)d_in[5], (const float*)d_in[6],
            (const float*)d_in[7], (const float*)d_in[8],
            (const float*)d_in[9], (const float*)d_in[10],
            (const float*)d_in[11], (const float*)d_in[12],
            (float*)d_out, nullptr);
    }
}

// Round 8
// 155.745 us; speedup vs baseline: 1.0628x; 1.0628x over previous
//
#include <hip/hip_runtime.h>
#include <cmath>

// Problem constants: B=32768, N=17, D=2, K=3, H=64
#define NBATCH 32768
#define NJOINT 17
#define OUT0_ELEMS (NBATCH * NJOINT * 15)          // out[B,N,3,5]
#define KJS_OFF    OUT0_ELEMS                      // k_js[B,N]
#define MASK_OFF   (KJS_OFF + NBATCH * NJOINT)     // mask[B,N,3]

// fp64 weight workspace (escape path only), per joint n stride 774 doubles:
//  [0,64) W1a | [64,128) W1b | [128,192) b1 | [192,384) W2[h][3] | [384,387) b2
//  +387 same for w-MLP
#define WN_STRIDE 774
#define WS_DOUBLES (NJOINT * WN_STRIDE)

__device__ __forceinline__ float sel3f(int i, float a, float b, float c) {
    return (i == 0) ? a : ((i == 1) ? b : c);
}

// --------------------------------------------------------------------------
// Prelude: fp64 copies of k/w weights (used only by the rare escape path).
// --------------------------------------------------------------------------
__global__ void cvt_weights_f64(
    const float* __restrict__ kW1, const float* __restrict__ kb1,
    const float* __restrict__ kW2, const float* __restrict__ kb2,
    const float* __restrict__ wW1, const float* __restrict__ wb1,
    const float* __restrict__ wW2, const float* __restrict__ wb2,
    double* __restrict__ dws)
{
    const int n = blockIdx.x;
    double* o = dws + (size_t)n * WN_STRIDE;
    for (int i = threadIdx.x; i < WN_STRIDE; i += blockDim.x) {
        int j = i;
        const float* W1 = kW1; const float* b1 = kb1;
        const float* W2 = kW2; const float* b2 = kb2;
        if (j >= 387) { j -= 387; W1 = wW1; b1 = wb1; W2 = wW2; b2 = wb2; }
        float v;
        if (j < 128)      v = W1[n * 128 + j];
        else if (j < 192) v = b1[n * 64 + (j - 128)];
        else if (j < 384) v = W2[n * 192 + (j - 192)];
        else              v = b2[n * 3 + (j - 384)];
        o[i] = (double)v;
    }
}

// --------------------------------------------------------------------------
// fp32 MLP (2 -> 64 -> 3) for TWO points, one s_load weight stream (r7-proven).
// --------------------------------------------------------------------------
__device__ __forceinline__ void mlp32_2(
    const float* __restrict__ W1, const float* __restrict__ b1f,
    const float* __restrict__ W2f, const float* __restrict__ b2f, int n,
    float xA0, float xA1, float xB0, float xB1,
    float& lA0, float& lA1, float& lA2,
    float& lB0, float& lB1, float& lB2)
{
    const float* W1a = W1 + n * 128;
    const float* W1b = W1a + 64;
    const float* b1  = b1f + n * 64;
    const float* W2  = W2f + n * 192;
    lA0 = b2f[n * 3 + 0]; lB0 = lA0;
    lA1 = b2f[n * 3 + 1]; lB1 = lA1;
    lA2 = b2f[n * 3 + 2]; lB2 = lA2;
    #pragma unroll 4
    for (int h = 0; h < 64; ++h) {
        const float wa = W1a[h], wb = W1b[h], bb = b1[h];
        const float w0 = W2[h * 3 + 0], w1 = W2[h * 3 + 1], w2 = W2[h * 3 + 2];
        float hvA = fmaxf(fmaf(xA1, wb, fmaf(xA0, wa, bb)), 0.0f);
        float hvB = fmaxf(fmaf(xB1, wb, fmaf(xB0, wa, bb)), 0.0f);
        lA0 = fmaf(hvA, w0, lA0); lB0 = fmaf(hvB, w0, lB0);
        lA1 = fmaf(hvA, w1, lA1); lB1 = fmaf(hvB, w1, lB1);
        lA2 = fmaf(hvA, w2, lA2); lB2 = fmaf(hvB, w2, lB2);
    }
}

// --------------------------------------------------------------------------
// fp64 escape: EXACT sequence of the proven passing kernels.
// --------------------------------------------------------------------------
__device__ __forceinline__ void mlp64_ws_1(
    const double* __restrict__ gws, double x0, double x1,
    double& l0, double& l1, double& l2)
{
    const double* W1a = gws;
    const double* W1b = gws + 64;
    const double* b1  = gws + 128;
    const double* W2  = gws + 192;
    l0 = gws[384]; l1 = gws[385]; l2 = gws[386];
    #pragma unroll 4
    for (int h = 0; h < 64; ++h) {
        double hv = fmax(fma(x1, W1b[h], fma(x0, W1a[h], b1[h])), 0.0);
        l0 = fma(hv, W2[h * 3 + 0], l0);
        l1 = fma(hv, W2[h * 3 + 1], l1);
        l2 = fma(hv, W2[h * 3 + 2], l2);
    }
}

__device__ __forceinline__ void mlp64_cvt_1(
    const float* __restrict__ W1, const float* __restrict__ b1f,
    const float* __restrict__ W2f, const float* __restrict__ b2f, int n,
    double x0, double x1, double& l0, double& l1, double& l2)
{
    const float* W1a = W1 + n * 128;
    const float* W1b = W1a + 64;
    const float* b1  = b1f + n * 64;
    const float* W2  = W2f + n * 192;
    l0 = (double)b2f[n * 3 + 0];
    l1 = (double)b2f[n * 3 + 1];
    l2 = (double)b2f[n * 3 + 2];
    #pragma unroll 4
    for (int h = 0; h < 64; ++h) {
        double hv = fma(x1, (double)W1b[h], fma(x0, (double)W1a[h], (double)b1[h]));
        hv = fmax(hv, 0.0);
        l0 = fma(hv, (double)W2[h * 3 + 0], l0);
        l1 = fma(hv, (double)W2[h * 3 + 1], l1);
        l2 = fma(hv, (double)W2[h * 3 + 2], l2);
    }
}

// margin check (r7-proven): any logit pair too close to trust fp32 ordering.
__device__ __forceinline__ bool tight3(float a, float b, float c) {
    const float m01 = fabsf(a - b), m02 = fabsf(a - c), m12 = fabsf(b - c);
    const float mn = fminf(m01, fminf(m02, m12));
    const float tau = 1e-3f * (1.0f + 0.02f * (fabsf(a) + fabsf(b) + fabsf(c)));
    return mn < tau;
}

// decisions + softmax from (double) logits — identical to passing kernels.
__device__ __forceinline__ void decide(
    double kl0, double kl1, double kl2,
    double wl0, double wl1, double wl2,
    int& kj, int& i0, int& i1, int& i2,
    float& p0, float& p1, float& p2)
{
    kj = 0;
    {
        double m = kl0;
        if (kl1 > m) { m = kl1; kj = 1; }
        if (kl2 > m) { kj = 2; }
    }
    i0 = 0;
    {
        double m = wl0;
        if (wl1 > m) { m = wl1; i0 = 1; }
        if (wl2 > m) { i0 = 2; }
    }
    const int ia = (i0 == 0) ? 1 : 0;
    const int ib = (i0 == 2) ? 1 : 2;
    const double wa = ia ? wl1 : wl0;
    const double wb = (ib == 1) ? wl1 : wl2;
    i1 = (wb > wa) ? ib : ia;
    i2 = (wb > wa) ? ia : ib;

    const double mw = fmax(fmax(wl0, wl1), wl2);
    const float e0 = __expf((float)(wl0 - mw));
    const float e1 = __expf((float)(wl1 - mw));
    const float e2 = __expf((float)(wl2 - mw));
    const float inv = 1.0f / (e0 + e1 + e2);
    p0 = e0 * inv; p1 = e1 * inv; p2 = e2 * inv;
}

__device__ __forceinline__ void epilogue(
    const float acc[12], int i0, int i1, int i2,
    float p0, float p1, float p2, float r[15])
{
    r[0]  = p0; r[5] = p1; r[10] = p2;
    r[1]  = sel3f(i0, acc[0], acc[4], acc[8]);
    r[2]  = sel3f(i0, acc[1], acc[5], acc[9]);
    r[3]  = __expf(sel3f(i0, acc[2], acc[6], acc[10]));
    r[4]  = __expf(sel3f(i0, acc[3], acc[7], acc[11]));
    r[6]  = sel3f(i1, acc[0], acc[4], acc[8]);
    r[7]  = sel3f(i1, acc[1], acc[5], acc[9]);
    r[8]  = __expf(sel3f(i1, acc[2], acc[6], acc[10]));
    r[9]  = __expf(sel3f(i1, acc[3], acc[7], acc[11]));
    r[11] = sel3f(i2, acc[0], acc[4], acc[8]);
    r[12] = sel3f(i2, acc[1], acc[5], acc[9]);
    r[13] = __expf(sel3f(i2, acc[2], acc[6], acc[10]));
    r[14] = __expf(sel3f(i2, acc[3], acc[7], acc[11]));
}

// --------------------------------------------------------------------------
// Two points per lane. fp32 k/w MLPs (halves scalar stream AND VALU cycles)
// with rare per-point fp64 escape; bMLP fp32 via s_load (r6-proven loop).
// --------------------------------------------------------------------------
template<bool USE_WS>
__device__ __forceinline__ void compute2(
    int n, float xA0f, float xA1f, float xB0f, float xB1f,
    const float* __restrict__ kW1, const float* __restrict__ kb1,
    const float* __restrict__ kW2, const float* __restrict__ kb2,
    const float* __restrict__ wW1, const float* __restrict__ wb1,
    const float* __restrict__ wW2, const float* __restrict__ wb2,
    const float* __restrict__ bW1, const float* __restrict__ bb1,
    const float* __restrict__ bW2, const float* __restrict__ bb2,
    const double* __restrict__ dws,
    float rA[15], float rB[15], int& kjA, int& kjB)
{
    // ---- k & w MLPs in fp32 (shared s_load stream, 2 pts) ----
    float kA0, kA1, kA2, kB0, kB1, kB2;
    float wA0, wA1, wA2, wB0, wB1, wB2;
    mlp32_2(kW1, kb1, kW2, kb2, n, xA0f, xA1f, xB0f, xB1f,
            kA0, kA1, kA2, kB0, kB1, kB2);
    mlp32_2(wW1, wb1, wW2, wb2, n, xA0f, xA1f, xB0f, xB1f,
            wA0, wA1, wA2, wB0, wB1, wB2);

    const bool fA = tight3(kA0, kA1, kA2) || tight3(wA0, wA1, wA2);
    const bool fB = tight3(kB0, kB1, kB2) || tight3(wB0, wB1, wB2);

    double klA0 = kA0, klA1 = kA1, klA2 = kA2;
    double klB0 = kB0, klB1 = kB1, klB2 = kB2;
    double wlA0 = wA0, wlA1 = wA1, wlA2 = wA2;
    double wlB0 = wB0, wlB1 = wB1, wlB2 = wB2;

    if (__any(fA || fB)) {             // rare: exact fp64 redo for flagged pts
        if constexpr (USE_WS) {
            const double* Wn = dws + (size_t)n * WN_STRIDE;
            if (fA) {
                mlp64_ws_1(Wn,       (double)xA0f, (double)xA1f, klA0, klA1, klA2);
                mlp64_ws_1(Wn + 387, (double)xA0f, (double)xA1f, wlA0, wlA1, wlA2);
            }
            if (fB) {
                mlp64_ws_1(Wn,       (double)xB0f, (double)xB1f, klB0, klB1, klB2);
                mlp64_ws_1(Wn + 387, (double)xB0f, (double)xB1f, wlB0, wlB1, wlB2);
            }
        } else {
            if (fA) {
                mlp64_cvt_1(kW1, kb1, kW2, kb2, n, (double)xA0f, (double)xA1f, klA0, klA1, klA2);
                mlp64_cvt_1(wW1, wb1, wW2, wb2, n, (double)xA0f, (double)xA1f, wlA0, wlA1, wlA2);
            }
            if (fB) {
                mlp64_cvt_1(kW1, kb1, kW2, kb2, n, (double)xB0f, (double)xB1f, klB0, klB1, klB2);
                mlp64_cvt_1(wW1, wb1, wW2, wb2, n, (double)xB0f, (double)xB1f, wlB0, wlB1, wlB2);
            }
        }
    }

    int i0A, i1A, i2A, i0B, i1B, i2B;
    float p0A, p1A, p2A, p0B, p1B, p2B;
    decide(klA0, klA1, klA2, wlA0, wlA1, wlA2, kjA, i0A, i1A, i2A, p0A, p1A, p2A);
    decide(klB0, klB1, klB2, wlB0, wlB1, wlB2, kjB, i0B, i1B, i2B, p0B, p1B, p2B);

    // ---- bMLP (fp32): 2 -> 128 -> 12, shared s_load stream (r6-proven) ----
    float accA[12], accB[12];
    {
        const float* W1a = bW1 + n * 256;
        const float* W1b = W1a + 128;
        const float* b1  = bb1 + n * 128;
        const float* W2  = bW2 + n * 1536;
        const float* b2  = bb2 + n * 12;
        #pragma unroll
        for (int j = 0; j < 12; ++j) { accA[j] = b2[j]; accB[j] = b2[j]; }
        #pragma unroll 4
        for (int h = 0; h < 128; ++h) {
            const float wa = W1a[h], wb = W1b[h], bb = b1[h];
            float hvA = fmaxf(fmaf(xA1f, wb, fmaf(xA0f, wa, bb)), 0.0f);
            float hvB = fmaxf(fmaf(xB1f, wb, fmaf(xB0f, wa, bb)), 0.0f);
            #pragma unroll
            for (int j = 0; j < 12; ++j) {
                const float wv = W2[h * 12 + j];
                accA[j] = fmaf(hvA, wv, accA[j]);
                accB[j] = fmaf(hvB, wv, accB[j]);
            }
        }
    }

    epilogue(accA, i0A, i1A, i2A, p0A, p1A, p2A, rA);
    epilogue(accB, i0B, i1B, i2B, p0B, p1B, p2B, rB);
}

// --------------------------------------------------------------------------
// Block = 2 waves (128 threads) = 2 n x 128 b tile, 2 pts/lane (r6-proven
// structure: 2304-block grid -> 9 blocks/CU balance, 17408B LDS staging,
// coalesced 120B-per-b write-back).
// --------------------------------------------------------------------------
template<bool USE_WS>
__global__ __launch_bounds__(128, 4) void mdn_fused(
    const float* __restrict__ pred_pts,
    const float* __restrict__ kW1, const float* __restrict__ kb1,
    const float* __restrict__ kW2, const float* __restrict__ kb2,
    const float* __restrict__ wW1, const float* __restrict__ wb1,
    const float* __restrict__ wW2, const float* __restrict__ wb2,
    const float* __restrict__ bW1, const float* __restrict__ bb1,
    const float* __restrict__ bW2, const float* __restrict__ bb2,
    float* __restrict__ out,
    const double* __restrict__ dws)
{
    const int l    = threadIdx.x;
    const int w    = l >> 6;           // wave id 0..1
    const int lane = l & 63;
    const int bx   = blockIdx.x;       // 0..255
    const int by   = blockIdx.y;       // 0..8
    const int n0   = by * 2;

    if (by == 8 && w == 1) return;     // before any barrier; wave 0 never barriers on by==8
    int n = n0 + w;                    // by==8: w==0 -> n=16
    n = __builtin_amdgcn_readfirstlane(n);

    const int bA = bx * 128 + lane;
    const int bB = bA + 64;
    const int pA = bA * NJOINT + n;
    const int pB = bB * NJOINT + n;

    const float2 xA = *reinterpret_cast<const float2*>(pred_pts + 2 * pA);
    const float2 xB = *reinterpret_cast<const float2*>(pred_pts + 2 * pB);

    float rA[15], rB[15];
    int kjA, kjB;
    compute2<USE_WS>(n, xA.x, xA.y, xB.x, xB.y,
                     kW1, kb1, kW2, kb2, wW1, wb1, wW2, wb2,
                     bW1, bb1, bW2, bb2, dws, rA, rB, kjA, kjB);

    if (by == 8) {
        // n==16 remainder (1/17 of points): direct stores, no barriers.
        float* oA = out + (size_t)pA * 15;
        float* oB = out + (size_t)pB * 15;
        #pragma unroll
        for (int i = 0; i < 15; ++i) { oA[i] = rA[i]; oB[i] = rB[i]; }
        out[KJS_OFF + pA] = (float)(kjA + 1);
        out[KJS_OFF + pB] = (float)(kjB + 1);
        float* mkA = out + MASK_OFF + (size_t)pA * 3;
        mkA[0] = 1.0f; mkA[1] = (kjA >= 1) ? 1.0f : 0.0f; mkA[2] = (kjA >= 2) ? 1.0f : 0.0f;
        float* mkB = out + MASK_OFF + (size_t)pB * 3;
        mkB[0] = 1.0f; mkB[1] = (kjB >= 1) ? 1.0f : 0.0f; mkB[2] = (kjB >= 2) ? 1.0f : 0.0f;
        return;
    }

    // ---- stage tile in LDS: slot = w*128 + local_b, stride 17 dwords ----
    __shared__ float s_out[256 * 17];  // 17408 B
    {
        float* soA = s_out + (w * 128 + lane) * 17;
        float* soB = soA + 64 * 17;
        #pragma unroll
        for (int j = 0; j < 15; ++j) { soA[j] = rA[j]; soB[j] = rB[j]; }
        soA[15] = (float)(kjA + 1);
        soB[15] = (float)(kjB + 1);
    }
    __syncthreads();

    // ---- coalesced write-back: 32 rounds, lanes 0..119 ----
    if (l < 120) {
        const int c_off = l / 30;              // 0..3
        const int jj    = l - c_off * 30;      // 0..29
        const int nl    = jj / 15;             // 0..1
        const int j     = jj - nl * 15;        // 0..14
        const int lbase = (nl * 128 + c_off) * 17 + j;
        size_t g = (size_t)((bx * 128 + c_off) * NJOINT + n0) * 15 + jj;
        #pragma unroll
        for (int rr = 0; rr < 32; ++rr) {
            out[g] = s_out[lbase + 68 * rr];   // b_local += 4 -> +4*17 dwords
            g += 1020;                          // 4 * 17 * 15 dwords
        }
    }

    // ---- k_js + mask from staged kj, per-b contiguous pairs ----
    #pragma unroll
    for (int it = 0; it < 2; ++it) {
        const int q   = it * 128 + l;          // 0..255
        const int bl  = q >> 1;                // 0..127
        const int nlr = q & 1;                 // 0..1
        const float kjf = s_out[(nlr * 128 + bl) * 17 + 15];
        const int pg = (bx * 128 + bl) * NJOINT + n0 + nlr;
        out[KJS_OFF + pg] = kjf;
        float* mk = out + MASK_OFF + (size_t)pg * 3;
        mk[0] = 1.0f;
        mk[1] = (kjf >= 1.5f) ? 1.0f : 0.0f;
        mk[2] = (kjf >= 2.5f) ? 1.0f : 0.0f;
    }
}

extern "C" void kernel_launch(void* const* d_in, const int* in_sizes, int n_in,
                              void* d_out, int out_size, void* d_ws, size_t ws_size,
                              hipStream_t stream) {
    (void)in_sizes; (void)n_in; (void)out_size;
    const bool use_ws = (d_ws != nullptr) && (ws_size >= (size_t)WS_DOUBLES * sizeof(double));
    dim3 grid(NBATCH / 128, 9);
    if (use_ws) {
        cvt_weights_f64<<<NJOINT, 256, 0, stream>>>(
            (const float*)d_in[1], (const float*)d_in[2],
            (const float*)d_in[3], (const float*)d_in[4],
            (const float*)d_in[5], (const float*)d_in[6],
            (const float*)d_in[7], (const float*)d_in[8],
            (double*)d_ws);
        mdn_fused<true><<<grid, 128, 0, stream>>>(
            (const float*)d_in[0],
            (const float*)d_in[1], (const float*)d_in[2],
            (const float*)d_in[3], (const float*)d_in[4],
            (const float*)d_in[5], (const float*)d_in[6],
            (const float*)d_in[7], (const float*)d_in[8],
            (const float*)d_in[9], (const float*)d_in[10],
            (const float*)d_in[11], (const float*)d_in[12],
            (float*)d_out, (const double*)d_ws);
    } else {
        mdn_fused<false><<<grid, 128, 0, stream>>>(
            (const float*)d_in[0],
            (const float*)d_in[1], (const float*)d_in[2],
            (const float*)d_in[3], (const float*)d_in[4],
            (const float*)d_in[5], (const float*)d_in[6],
            (const float*)d_in[7], (const float*)d_in[8],
            (const float*)d_in[9], (const float*)d_in[10],
            (const float*)d_in[11], (const float*)d_in[12],
            (float*)d_out, nullptr);
    }
}

// Round 9
// 145.579 us; speedup vs baseline: 1.1370x; 1.0698x over previous
//
#include <hip/hip_runtime.h>
#include <cmath>

// Problem constants: B=32768, N=17, D=2, K=3, H=64
#define NBATCH 32768
#define NJOINT 17
#define OUT0_ELEMS (NBATCH * NJOINT * 15)          // out[B,N,3,5]
#define KJS_OFF    OUT0_ELEMS                      // k_js[B,N]
#define MASK_OFF   (KJS_OFF + NBATCH * NJOINT)     // mask[B,N,3]

// fp64 weight workspace (escape path only), per joint n stride 774 doubles:
//  [0,64) W1a | [64,128) W1b | [128,192) b1 | [192,384) W2[h][3] | [384,387) b2
//  +387 same for w-MLP
#define WN_STRIDE 774
#define WS_DOUBLES (NJOINT * WN_STRIDE)

__device__ __forceinline__ float sel3f(int i, float a, float b, float c) {
    return (i == 0) ? a : ((i == 1) ? b : c);
}

// --------------------------------------------------------------------------
// Prelude: fp64 copies of k/w weights (used only by the rare escape path).
// --------------------------------------------------------------------------
__global__ void cvt_weights_f64(
    const float* __restrict__ kW1, const float* __restrict__ kb1,
    const float* __restrict__ kW2, const float* __restrict__ kb2,
    const float* __restrict__ wW1, const float* __restrict__ wb1,
    const float* __restrict__ wW2, const float* __restrict__ wb2,
    double* __restrict__ dws)
{
    const int n = blockIdx.x;
    double* o = dws + (size_t)n * WN_STRIDE;
    for (int i = threadIdx.x; i < WN_STRIDE; i += blockDim.x) {
        int j = i;
        const float* W1 = kW1; const float* b1 = kb1;
        const float* W2 = kW2; const float* b2 = kb2;
        if (j >= 387) { j -= 387; W1 = wW1; b1 = wb1; W2 = wW2; b2 = wb2; }
        float v;
        if (j < 128)      v = W1[n * 128 + j];
        else if (j < 192) v = b1[n * 64 + (j - 128)];
        else if (j < 384) v = W2[n * 192 + (j - 192)];
        else              v = b2[n * 3 + (j - 384)];
        o[i] = (double)v;
    }
}

// --------------------------------------------------------------------------
// fp32 MLP (2 -> 64 -> 3) for TWO points, one s_load weight stream.
// --------------------------------------------------------------------------
__device__ __forceinline__ void mlp32_2(
    const float* __restrict__ W1, const float* __restrict__ b1f,
    const float* __restrict__ W2f, const float* __restrict__ b2f, int n,
    float xA0, float xA1, float xB0, float xB1,
    float& lA0, float& lA1, float& lA2,
    float& lB0, float& lB1, float& lB2)
{
    const float* W1a = W1 + n * 128;
    const float* W1b = W1a + 64;
    const float* b1  = b1f + n * 64;
    const float* W2  = W2f + n * 192;
    lA0 = b2f[n * 3 + 0]; lB0 = lA0;
    lA1 = b2f[n * 3 + 1]; lB1 = lA1;
    lA2 = b2f[n * 3 + 2]; lB2 = lA2;
    #pragma unroll 4
    for (int h = 0; h < 64; ++h) {
        const float wa = W1a[h], wb = W1b[h], bb = b1[h];
        const float w0 = W2[h * 3 + 0], w1 = W2[h * 3 + 1], w2 = W2[h * 3 + 2];
        float hvA = fmaxf(fmaf(xA1, wb, fmaf(xA0, wa, bb)), 0.0f);
        float hvB = fmaxf(fmaf(xB1, wb, fmaf(xB0, wa, bb)), 0.0f);
        lA0 = fmaf(hvA, w0, lA0); lB0 = fmaf(hvB, w0, lB0);
        lA1 = fmaf(hvA, w1, lA1); lB1 = fmaf(hvB, w1, lB1);
        lA2 = fmaf(hvA, w2, lA2); lB2 = fmaf(hvB, w2, lB2);
    }
}

// --------------------------------------------------------------------------
// fp64 escape: EXACT sequence of the proven passing kernels.
// --------------------------------------------------------------------------
__device__ __forceinline__ void mlp64_ws_1(
    const double* __restrict__ gws, double x0, double x1,
    double& l0, double& l1, double& l2)
{
    const double* W1a = gws;
    const double* W1b = gws + 64;
    const double* b1  = gws + 128;
    const double* W2  = gws + 192;
    l0 = gws[384]; l1 = gws[385]; l2 = gws[386];
    #pragma unroll 4
    for (int h = 0; h < 64; ++h) {
        double hv = fmax(fma(x1, W1b[h], fma(x0, W1a[h], b1[h])), 0.0);
        l0 = fma(hv, W2[h * 3 + 0], l0);
        l1 = fma(hv, W2[h * 3 + 1], l1);
        l2 = fma(hv, W2[h * 3 + 2], l2);
    }
}

__device__ __forceinline__ void mlp64_cvt_1(
    const float* __restrict__ W1, const float* __restrict__ b1f,
    const float* __restrict__ W2f, const float* __restrict__ b2f, int n,
    double x0, double x1, double& l0, double& l1, double& l2)
{
    const float* W1a = W1 + n * 128;
    const float* W1b = W1a + 64;
    const float* b1  = b1f + n * 64;
    const float* W2  = W2f + n * 192;
    l0 = (double)b2f[n * 3 + 0];
    l1 = (double)b2f[n * 3 + 1];
    l2 = (double)b2f[n * 3 + 2];
    #pragma unroll 4
    for (int h = 0; h < 64; ++h) {
        double hv = fma(x1, (double)W1b[h], fma(x0, (double)W1a[h], (double)b1[h]));
        hv = fmax(hv, 0.0);
        l0 = fma(hv, (double)W2[h * 3 + 0], l0);
        l1 = fma(hv, (double)W2[h * 3 + 1], l1);
        l2 = fma(hv, (double)W2[h * 3 + 2], l2);
    }
}

// margin check: any logit pair too close to trust fp32 ordering vs fp64.
// fp32/fp64 divergence of this 192-fma chain is ~5e-7 rms (worst case ~1e-4
// needs all roundings aligned). tau = 2e-5*(1+0.05*sum|l|) is ~40x rms while
// keeping the per-wave escape probability ~3% (r8's 1e-3 escaped on 79% of
// waves and re-fetched the full fp64 stream -> slower than pure fp64).
__device__ __forceinline__ bool tight3(float a, float b, float c) {
    const float m01 = fabsf(a - b), m02 = fabsf(a - c), m12 = fabsf(b - c);
    const float mn = fminf(m01, fminf(m02, m12));
    const float tau = 2e-5f * (1.0f + 0.05f * (fabsf(a) + fabsf(b) + fabsf(c)));
    return mn < tau;
}

// decisions + softmax from (double) logits — identical to passing kernels.
__device__ __forceinline__ void decide(
    double kl0, double kl1, double kl2,
    double wl0, double wl1, double wl2,
    int& kj, int& i0, int& i1, int& i2,
    float& p0, float& p1, float& p2)
{
    kj = 0;
    {
        double m = kl0;
        if (kl1 > m) { m = kl1; kj = 1; }
        if (kl2 > m) { kj = 2; }
    }
    i0 = 0;
    {
        double m = wl0;
        if (wl1 > m) { m = wl1; i0 = 1; }
        if (wl2 > m) { i0 = 2; }
    }
    const int ia = (i0 == 0) ? 1 : 0;
    const int ib = (i0 == 2) ? 1 : 2;
    const double wa = ia ? wl1 : wl0;
    const double wb = (ib == 1) ? wl1 : wl2;
    i1 = (wb > wa) ? ib : ia;
    i2 = (wb > wa) ? ia : ib;

    const double mw = fmax(fmax(wl0, wl1), wl2);
    const float e0 = __expf((float)(wl0 - mw));
    const float e1 = __expf((float)(wl1 - mw));
    const float e2 = __expf((float)(wl2 - mw));
    const float inv = 1.0f / (e0 + e1 + e2);
    p0 = e0 * inv; p1 = e1 * inv; p2 = e2 * inv;
}

__device__ __forceinline__ void epilogue(
    const float acc[12], int i0, int i1, int i2,
    float p0, float p1, float p2, float r[15])
{
    r[0]  = p0; r[5] = p1; r[10] = p2;
    r[1]  = sel3f(i0, acc[0], acc[4], acc[8]);
    r[2]  = sel3f(i0, acc[1], acc[5], acc[9]);
    r[3]  = __expf(sel3f(i0, acc[2], acc[6], acc[10]));
    r[4]  = __expf(sel3f(i0, acc[3], acc[7], acc[11]));
    r[6]  = sel3f(i1, acc[0], acc[4], acc[8]);
    r[7]  = sel3f(i1, acc[1], acc[5], acc[9]);
    r[8]  = __expf(sel3f(i1, acc[2], acc[6], acc[10]));
    r[9]  = __expf(sel3f(i1, acc[3], acc[7], acc[11]));
    r[11] = sel3f(i2, acc[0], acc[4], acc[8]);
    r[12] = sel3f(i2, acc[1], acc[5], acc[9]);
    r[13] = __expf(sel3f(i2, acc[2], acc[6], acc[10]));
    r[14] = __expf(sel3f(i2, acc[3], acc[7], acc[11]));
}

// --------------------------------------------------------------------------
// Two points per lane. fp32 k/w MLPs with RARE (~3% of waves) fp64 escape;
// bMLP fp32 via s_load (r6-proven loop).
// --------------------------------------------------------------------------
template<bool USE_WS>
__device__ __forceinline__ void compute2(
    int n, float xA0f, float xA1f, float xB0f, float xB1f,
    const float* __restrict__ kW1, const float* __restrict__ kb1,
    const float* __restrict__ kW2, const float* __restrict__ kb2,
    const float* __restrict__ wW1, const float* __restrict__ wb1,
    const float* __restrict__ wW2, const float* __restrict__ wb2,
    const float* __restrict__ bW1, const float* __restrict__ bb1,
    const float* __restrict__ bW2, const float* __restrict__ bb2,
    const double* __restrict__ dws,
    float rA[15], float rB[15], int& kjA, int& kjB)
{
    // ---- k & w MLPs in fp32 (shared s_load stream, 2 pts) ----
    float kA0, kA1, kA2, kB0, kB1, kB2;
    float wA0, wA1, wA2, wB0, wB1, wB2;
    mlp32_2(kW1, kb1, kW2, kb2, n, xA0f, xA1f, xB0f, xB1f,
            kA0, kA1, kA2, kB0, kB1, kB2);
    mlp32_2(wW1, wb1, wW2, wb2, n, xA0f, xA1f, xB0f, xB1f,
            wA0, wA1, wA2, wB0, wB1, wB2);

    const bool fA = tight3(kA0, kA1, kA2) || tight3(wA0, wA1, wA2);
    const bool fB = tight3(kB0, kB1, kB2) || tight3(wB0, wB1, wB2);

    double klA0 = kA0, klA1 = kA1, klA2 = kA2;
    double klB0 = kB0, klB1 = kB1, klB2 = kB2;
    double wlA0 = wA0, wlA1 = wA1, wlA2 = wA2;
    double wlB0 = wB0, wlB1 = wB1, wlB2 = wB2;

    if (__any(fA || fB)) {             // ~3% of waves: exact fp64 redo
        if constexpr (USE_WS) {
            const double* Wn = dws + (size_t)n * WN_STRIDE;
            if (fA) {
                mlp64_ws_1(Wn,       (double)xA0f, (double)xA1f, klA0, klA1, klA2);
                mlp64_ws_1(Wn + 387, (double)xA0f, (double)xA1f, wlA0, wlA1, wlA2);
            }
            if (fB) {
                mlp64_ws_1(Wn,       (double)xB0f, (double)xB1f, klB0, klB1, klB2);
                mlp64_ws_1(Wn + 387, (double)xB0f, (double)xB1f, wlB0, wlB1, wlB2);
            }
        } else {
            if (fA) {
                mlp64_cvt_1(kW1, kb1, kW2, kb2, n, (double)xA0f, (double)xA1f, klA0, klA1, klA2);
                mlp64_cvt_1(wW1, wb1, wW2, wb2, n, (double)xA0f, (double)xA1f, wlA0, wlA1, wlA2);
            }
            if (fB) {
                mlp64_cvt_1(kW1, kb1, kW2, kb2, n, (double)xB0f, (double)xB1f, klB0, klB1, klB2);
                mlp64_cvt_1(wW1, wb1, wW2, wb2, n, (double)xB0f, (double)xB1f, wlB0, wlB1, wlB2);
            }
        }
    }

    int i0A, i1A, i2A, i0B, i1B, i2B;
    float p0A, p1A, p2A, p0B, p1B, p2B;
    decide(klA0, klA1, klA2, wlA0, wlA1, wlA2, kjA, i0A, i1A, i2A, p0A, p1A, p2A);
    decide(klB0, klB1, klB2, wlB0, wlB1, wlB2, kjB, i0B, i1B, i2B, p0B, p1B, p2B);

    // ---- bMLP (fp32): 2 -> 128 -> 12, shared s_load stream (r6-proven) ----
    float accA[12], accB[12];
    {
        const float* W1a = bW1 + n * 256;
        const float* W1b = W1a + 128;
        const float* b1  = bb1 + n * 128;
        const float* W2  = bW2 + n * 1536;
        const float* b2  = bb2 + n * 12;
        #pragma unroll
        for (int j = 0; j < 12; ++j) { accA[j] = b2[j]; accB[j] = b2[j]; }
        #pragma unroll 4
        for (int h = 0; h < 128; ++h) {
            const float wa = W1a[h], wb = W1b[h], bb = b1[h];
            float hvA = fmaxf(fmaf(xA1f, wb, fmaf(xA0f, wa, bb)), 0.0f);
            float hvB = fmaxf(fmaf(xB1f, wb, fmaf(xB0f, wa, bb)), 0.0f);
            #pragma unroll
            for (int j = 0; j < 12; ++j) {
                const float wv = W2[h * 12 + j];
                accA[j] = fmaf(hvA, wv, accA[j]);
                accB[j] = fmaf(hvB, wv, accB[j]);
            }
        }
    }

    epilogue(accA, i0A, i1A, i2A, p0A, p1A, p2A, rA);
    epilogue(accB, i0B, i1B, i2B, p0B, p1B, p2B, rB);
}

// --------------------------------------------------------------------------
// Block = 2 waves (128 threads) = 2 n x 128 b tile, 2 pts/lane (r6-proven
// structure: 2304-block grid, 17408B LDS staging, coalesced write-back).
// --------------------------------------------------------------------------
template<bool USE_WS>
__global__ __launch_bounds__(128, 4) void mdn_fused(
    const float* __restrict__ pred_pts,
    const float* __restrict__ kW1, const float* __restrict__ kb1,
    const float* __restrict__ kW2, const float* __restrict__ kb2,
    const float* __restrict__ wW1, const float* __restrict__ wb1,
    const float* __restrict__ wW2, const float* __restrict__ wb2,
    const float* __restrict__ bW1, const float* __restrict__ bb1,
    const float* __restrict__ bW2, const float* __restrict__ bb2,
    float* __restrict__ out,
    const double* __restrict__ dws)
{
    const int l    = threadIdx.x;
    const int w    = l >> 6;           // wave id 0..1
    const int lane = l & 63;
    const int bx   = blockIdx.x;       // 0..255
    const int by   = blockIdx.y;       // 0..8
    const int n0   = by * 2;

    if (by == 8 && w == 1) return;     // before any barrier; wave 0 never barriers on by==8
    int n = n0 + w;                    // by==8: w==0 -> n=16
    n = __builtin_amdgcn_readfirstlane(n);

    const int bA = bx * 128 + lane;
    const int bB = bA + 64;
    const int pA = bA * NJOINT + n;
    const int pB = bB * NJOINT + n;

    const float2 xA = *reinterpret_cast<const float2*>(pred_pts + 2 * pA);
    const float2 xB = *reinterpret_cast<const float2*>(pred_pts + 2 * pB);

    float rA[15], rB[15];
    int kjA, kjB;
    compute2<USE_WS>(n, xA.x, xA.y, xB.x, xB.y,
                     kW1, kb1, kW2, kb2, wW1, wb1, wW2, wb2,
                     bW1, bb1, bW2, bb2, dws, rA, rB, kjA, kjB);

    if (by == 8) {
        // n==16 remainder (1/17 of points): direct stores, no barriers.
        float* oA = out + (size_t)pA * 15;
        float* oB = out + (size_t)pB * 15;
        #pragma unroll
        for (int i = 0; i < 15; ++i) { oA[i] = rA[i]; oB[i] = rB[i]; }
        out[KJS_OFF + pA] = (float)(kjA + 1);
        out[KJS_OFF + pB] = (float)(kjB + 1);
        float* mkA = out + MASK_OFF + (size_t)pA * 3;
        mkA[0] = 1.0f; mkA[1] = (kjA >= 1) ? 1.0f : 0.0f; mkA[2] = (kjA >= 2) ? 1.0f : 0.0f;
        float* mkB = out + MASK_OFF + (size_t)pB * 3;
        mkB[0] = 1.0f; mkB[1] = (kjB >= 1) ? 1.0f : 0.0f; mkB[2] = (kjB >= 2) ? 1.0f : 0.0f;
        return;
    }

    // ---- stage tile in LDS: slot = w*128 + local_b, stride 17 dwords ----
    __shared__ float s_out[256 * 17];  // 17408 B
    {
        float* soA = s_out + (w * 128 + lane) * 17;
        float* soB = soA + 64 * 17;
        #pragma unroll
        for (int j = 0; j < 15; ++j) { soA[j] = rA[j]; soB[j] = rB[j]; }
        soA[15] = (float)(kjA + 1);
        soB[15] = (float)(kjB + 1);
    }
    __syncthreads();

    // ---- coalesced write-back: 32 rounds, lanes 0..119 ----
    if (l < 120) {
        const int c_off = l / 30;              // 0..3
        const int jj    = l - c_off * 30;      // 0..29
        const int nl    = jj / 15;             // 0..1
        const int j     = jj - nl * 15;        // 0..14
        const int lbase = (nl * 128 + c_off) * 17 + j;
        size_t g = (size_t)((bx * 128 + c_off) * NJOINT + n0) * 15 + jj;
        #pragma unroll
        for (int rr = 0; rr < 32; ++rr) {
            out[g] = s_out[lbase + 68 * rr];   // b_local += 4 -> +4*17 dwords
            g += 1020;                          // 4 * 17 * 15 dwords
        }
    }

    // ---- k_js + mask from staged kj, per-b contiguous pairs ----
    #pragma unroll
    for (int it = 0; it < 2; ++it) {
        const int q   = it * 128 + l;          // 0..255
        const int bl  = q >> 1;                // 0..127
        const int nlr = q & 1;                 // 0..1
        const float kjf = s_out[(nlr * 128 + bl) * 17 + 15];
        const int pg = (bx * 128 + bl) * NJOINT + n0 + nlr;
        out[KJS_OFF + pg] = kjf;
        float* mk = out + MASK_OFF + (size_t)pg * 3;
        mk[0] = 1.0f;
        mk[1] = (kjf >= 1.5f) ? 1.0f : 0.0f;
        mk[2] = (kjf >= 2.5f) ? 1.0f : 0.0f;
    }
}

extern "C" void kernel_launch(void* const* d_in, const int* in_sizes, int n_in,
                              void* d_out, int out_size, void* d_ws, size_t ws_size,
                              hipStream_t stream) {
    (void)in_sizes; (void)n_in; (void)out_size;
    const bool use_ws = (d_ws != nullptr) && (ws_size >= (size_t)WS_DOUBLES * sizeof(double));
    dim3 grid(NBATCH / 128, 9);
    if (use_ws) {
        cvt_weights_f64<<<NJOINT, 256, 0, stream>>>(
            (const float*)d_in[1], (const float*)d_in[2],
            (const float*)d_in[3], (const float*)d_in[4],
            (const float*)d_in[5], (const float*)d_in[6],
            (const float*)d_in[7], (const float*)d_in[8],
            (double*)d_ws);
        mdn_fused<true><<<grid, 128, 0, stream>>>(
            (const float*)d_in[0],
            (const float*)d_in[1], (const float*)d_in[2],
            (const float*)d_in[3], (const float*)d_in[4],
            (const float*)d_in[5], (const float*)d_in[6],
            (const float*)d_in[7], (const float*)d_in[8],
            (const float*)d_in[9], (const float*)d_in[10],
            (const float*)d_in[11], (const float*)d_in[12],
            (float*)d_out, (const double*)d_ws);
    } else {
        mdn_fused<false><<<grid, 128, 0, stream>>>(
            (const float*)d_in[0],
            (const float*)d_in[1], (const float*)d_in[2],
            (const float*)d_in[3], (const float*)d_in[4],
            (const float*)d_in[5], (const float*)d_in[6],
            (const float*)d_in[7], (const float*)d_in[8],
            (const float*)d_in[9], (const float*)d_in[10],
            (const float*)d_in[11], (const float*)d_in[12],
            (float*)d_out, nullptr);
    }
}